// Round 1
// baseline (377.448 us; speedup 1.0000x reference)
//
#include <hip/hip_runtime.h>
#include <hip/hip_bf16.h>
#include <math.h>

// ---------- types ----------
typedef __attribute__((ext_vector_type(8))) short bf16x8;   // 8 bf16 in 4 VGPRs
typedef __attribute__((ext_vector_type(4))) float f32x4;

// ---------- helpers ----------
__device__ __forceinline__ unsigned short f2bf_rne(float f) {
    union { float f; unsigned u; } x; x.f = f;
    unsigned r = x.u + 0x7FFFu + ((x.u >> 16) & 1u);
    return (unsigned short)(r >> 16);
}
__device__ __forceinline__ float bf2f(unsigned short h) {
    union { unsigned u; float f; } x; x.u = ((unsigned)h) << 16;
    return x.f;
}
__device__ __forceinline__ void store_out(float* p, float v) { *p = v; }
__device__ __forceinline__ void store_out(unsigned short* p, float v) { *p = f2bf_rne(v); }

__device__ __forceinline__ void async_copy16(const void* g, void* l) {
    __builtin_amdgcn_global_load_lds(
        (const __attribute__((address_space(1))) void*)g,
        (__attribute__((address_space(3))) void*)l, 16, 0, 0);
}

// ---------- fp32 -> bf16 convert (vectorized float4 -> ushort4) ----------
__global__ __launch_bounds__(256) void cvt_f32_bf16(const float* __restrict__ in,
                                                    unsigned short* __restrict__ out,
                                                    int n4) {
    int i = blockIdx.x * 256 + threadIdx.x;
    if (i < n4) {
        float4 v = ((const float4*)in)[i];
        ushort4 o;
        o.x = f2bf_rne(v.x); o.y = f2bf_rne(v.y);
        o.z = f2bf_rne(v.z); o.w = f2bf_rne(v.w);
        ((ushort4*)out)[i] = o;
    }
}

// ---------- NT bf16 GEMM: C[m,n] = scale * sum_k A[m,k]*B[n,k] + bias[n] ----------
// 128x128 tile, BK=32, 256 threads = 4 waves in 2x2, 64x64 per wave,
// 4x4 MFMA 16x16x32 tiles per wave. m97-pattern global_load_lds staging.
template <typename OutT>
__global__ __launch_bounds__(256) void gemm_nt_bf16(
    const unsigned short* __restrict__ A, int lda, long long strideA,
    const unsigned short* __restrict__ B, int ldb, long long strideB,
    OutT* __restrict__ C, int ldc, long long strideC,
    const float* __restrict__ bias, float scale, int K)
{
    __shared__ unsigned short shA[128 * 32];
    __shared__ unsigned short shB[128 * 32];

    const int t    = threadIdx.x;
    const int lane = t & 63;
    const int wave = t >> 6;
    const int wm   = (wave & 1) * 64;   // wave row offset in tile
    const int wn   = (wave >> 1) * 64;  // wave col offset in tile
    const int quad = lane >> 4;
    const int l16  = lane & 15;

    const long long batch = blockIdx.z;
    A += batch * strideA;
    B += batch * strideB;
    C += batch * strideC;

    const long long tileM = (long long)blockIdx.y * 128;
    const long long tileN = (long long)blockIdx.x * 128;

    f32x4 acc[4][4];
#pragma unroll
    for (int i = 0; i < 4; ++i)
#pragma unroll
        for (int j = 0; j < 4; ++j)
#pragma unroll
            for (int r = 0; r < 4; ++r) acc[i][j][r] = 0.0f;

    for (int k0 = 0; k0 < K; k0 += 32) {
        __syncthreads();   // previous iter's frags consumed before overwrite
#pragma unroll
        for (int p = 0; p < 2; ++p) {
            const int chunk = p * 256 + t;      // lds dst = base + chunk*16B: lane-ordered
            const int row   = chunk >> 2;       // 0..127
            const int kk    = (chunk & 3) << 3; // 0,8,16,24
            async_copy16(A + (tileM + row) * (long long)lda + k0 + kk, &shA[chunk << 3]);
            async_copy16(B + (tileN + row) * (long long)ldb + k0 + kk, &shB[chunk << 3]);
        }
        __syncthreads();   // compiler drains vmcnt(0) before barrier

        bf16x8 af[4], bfr[4];
#pragma unroll
        for (int mi = 0; mi < 4; ++mi)
            af[mi] = *(const bf16x8*)(&shA[(wm + mi * 16 + l16) * 32 + quad * 8]);
#pragma unroll
        for (int ni = 0; ni < 4; ++ni)
            bfr[ni] = *(const bf16x8*)(&shB[(wn + ni * 16 + l16) * 32 + quad * 8]);
#pragma unroll
        for (int mi = 0; mi < 4; ++mi)
#pragma unroll
            for (int ni = 0; ni < 4; ++ni)
                acc[mi][ni] = __builtin_amdgcn_mfma_f32_16x16x32_bf16(
                    af[mi], bfr[ni], acc[mi][ni], 0, 0, 0);
    }

    // epilogue: D[m][n], m = quad*4 + reg, n = lane&15 within each 16x16 tile
#pragma unroll
    for (int ni = 0; ni < 4; ++ni) {
        const long long gn = tileN + wn + ni * 16 + l16;
        const float bv = bias ? bias[gn] : 0.0f;
#pragma unroll
        for (int mi = 0; mi < 4; ++mi) {
            const long long gm0 = tileM + wm + mi * 16 + quad * 4;
#pragma unroll
            for (int r = 0; r < 4; ++r) {
                float v = acc[mi][ni][r] * scale + bv;
                store_out(C + (gm0 + r) * (long long)ldc + gn, v);
            }
        }
    }
}

// ---------- row softmax in place on [rows][1024] bf16 ----------
__global__ __launch_bounds__(256) void softmax_inplace(unsigned short* __restrict__ att) {
    const long long row = blockIdx.x;
    unsigned short* p = att + row * 1024;
    const int t = threadIdx.x;
    const int wave = t >> 6, lane = t & 63;
    __shared__ float red[4];

    float v[4];
    float mx = -1e30f;
#pragma unroll
    for (int i = 0; i < 4; ++i) { v[i] = bf2f(p[t + i * 256]); mx = fmaxf(mx, v[i]); }
#pragma unroll
    for (int o = 32; o > 0; o >>= 1) mx = fmaxf(mx, __shfl_xor(mx, o));
    if (lane == 0) red[wave] = mx;
    __syncthreads();
    mx = fmaxf(fmaxf(red[0], red[1]), fmaxf(red[2], red[3]));

    float s = 0.f;
#pragma unroll
    for (int i = 0; i < 4; ++i) { v[i] = __expf(v[i] - mx); s += v[i]; }
#pragma unroll
    for (int o = 32; o > 0; o >>= 1) s += __shfl_xor(s, o);
    __syncthreads();   // red[] reuse
    if (lane == 0) red[wave] = s;
    __syncthreads();
    s = red[0] + red[1] + red[2] + red[3];
    const float inv = 1.0f / s;
#pragma unroll
    for (int i = 0; i < 4; ++i) p[t + i * 256] = f2bf_rne(v[i] * inv);
}

// ---------- V transpose: vt[b][d][k] = qkv[b][k][1536+d] ----------
__global__ __launch_bounds__(256) void transpose_v(const unsigned short* __restrict__ qkv,
                                                   unsigned short* __restrict__ vt) {
    __shared__ unsigned short tile[32][33];
    const int b  = blockIdx.z;
    const int k0 = blockIdx.x * 32;
    const int d0 = blockIdx.y * 32;
    const int x  = threadIdx.x;  // 32
    const int y  = threadIdx.y;  // 8
    const unsigned short* src = qkv + (long long)b * 1024 * 2304;
#pragma unroll
    for (int j = 0; j < 4; ++j) {
        int k = k0 + y + j * 8;
        tile[y + j * 8][x] = src[(long long)k * 2304 + 1536 + d0 + x];
    }
    __syncthreads();
    unsigned short* dst = vt + (long long)b * 768 * 1024;
#pragma unroll
    for (int j = 0; j < 4; ++j) {
        int d = d0 + y + j * 8;
        dst[(long long)d * 1024 + k0 + x] = tile[x][y + j * 8];
    }
}

// ---------- launcher ----------
extern "C" void kernel_launch(void* const* d_in, const int* in_sizes, int n_in,
                              void* d_out, int out_size, void* d_ws, size_t ws_size,
                              hipStream_t stream) {
    (void)in_sizes; (void)n_in; (void)out_size; (void)ws_size;

    const float* x     = (const float*)d_in[0];
    const float* w_qkv = (const float*)d_in[1];
    const float* b_qkv = (const float*)d_in[2];
    const float* w_out = (const float*)d_in[3];
    const float* b_out = (const float*)d_in[4];
    float* out = (float*)d_out;

    const int B = 16, S = 1024, D = 768;
    const long long MS = (long long)B * S;  // 16384 rows

    // workspace layout (bf16 = ushort), all 16B aligned
    unsigned short* xb   = (unsigned short*)d_ws;          // [16384][768]
    unsigned short* wqb  = xb   + MS * D;                  // [2304][768]
    unsigned short* wob  = wqb  + 3LL * D * D;             // [768][768]
    unsigned short* qkvb = wob  + (long long)D * D;        // [16384][2304]
    unsigned short* att  = qkvb + MS * 3 * D;              // [16][1024][1024]
    unsigned short* vt   = att  + (long long)B * S * S;    // [16][768][1024]
    unsigned short* ob   = vt   + (long long)B * D * S;    // [16384][768]

    // 1) converts
    {
        int n4 = (int)(MS * D / 4);
        cvt_f32_bf16<<<(n4 + 255) / 256, 256, 0, stream>>>(x, xb, n4);
        n4 = 3 * D * D / 4;
        cvt_f32_bf16<<<(n4 + 255) / 256, 256, 0, stream>>>(w_qkv, wqb, n4);
        n4 = D * D / 4;
        cvt_f32_bf16<<<(n4 + 255) / 256, 256, 0, stream>>>(w_out, wob, n4);
    }

    // 2) QKV = x @ Wqkv^T + b   [16384, 2304]
    gemm_nt_bf16<unsigned short><<<dim3(3 * D / 128, MS / 128, 1), 256, 0, stream>>>(
        xb, D, 0, wqb, D, 0, qkvb, 3 * D, 0, b_qkv, 1.0f, D);

    // 3) logits = scale * Q @ K^T   per batch [1024, 1024]
    const float scale = 0.03608439182435162f;  // 1/sqrt(768)
    gemm_nt_bf16<unsigned short><<<dim3(S / 128, S / 128, B), 256, 0, stream>>>(
        qkvb,     3 * D, (long long)S * 3 * D,
        qkvb + D, 3 * D, (long long)S * 3 * D,
        att, S, (long long)S * S, nullptr, scale, D);

    // 4) softmax rows in place
    softmax_inplace<<<(int)MS, 256, 0, stream>>>(att);

    // 5) vt[b][d][k] = v[b][k][d]
    transpose_v<<<dim3(S / 32, D / 32, B), dim3(32, 8), 0, stream>>>(qkvb, vt);

    // 6) O = P @ V   per batch [1024, 768]
    gemm_nt_bf16<unsigned short><<<dim3(D / 128, S / 128, B), 256, 0, stream>>>(
        att, S, (long long)S * S,
        vt,  S, (long long)D * S,
        ob,  D, (long long)S * D, nullptr, 1.0f, S);

    // 7) out = O @ Wout^T + b   [16384, 768] fp32
    gemm_nt_bf16<float><<<dim3(D / 128, MS / 128, 1), 256, 0, stream>>>(
        ob, D, 0, wob, D, 0, out, D, 0, b_out, 1.0f, D);
}

// Round 2
// 348.193 us; speedup vs baseline: 1.0840x; 1.0840x over previous
//
#include <hip/hip_runtime.h>
#include <hip/hip_bf16.h>
#include <math.h>

// ---------- types ----------
typedef __attribute__((ext_vector_type(8))) short bf16x8;   // 8 bf16 in 4 VGPRs
typedef __attribute__((ext_vector_type(4))) float f32x4;

// ---------- helpers ----------
__device__ __forceinline__ unsigned short f2bf_rne(float f) {
    union { float f; unsigned u; } x; x.f = f;
    unsigned r = x.u + 0x7FFFu + ((x.u >> 16) & 1u);
    return (unsigned short)(r >> 16);
}
__device__ __forceinline__ float bf2f(unsigned short h) {
    union { unsigned u; float f; } x; x.u = ((unsigned)h) << 16;
    return x.f;
}
__device__ __forceinline__ void store_out(float* p, float v) { *p = v; }
__device__ __forceinline__ void store_out(unsigned short* p, float v) { *p = f2bf_rne(v); }

__device__ __forceinline__ void async_copy16(const void* g, void* l) {
    __builtin_amdgcn_global_load_lds(
        (const __attribute__((address_space(1))) void*)g,
        (__attribute__((address_space(3))) void*)l, 16, 0, 0);
}

// ---------- fp32 -> bf16 convert (vectorized float4 -> ushort4) ----------
__global__ __launch_bounds__(256) void cvt_f32_bf16(const float* __restrict__ in,
                                                    unsigned short* __restrict__ out,
                                                    int n4) {
    int i = blockIdx.x * 256 + threadIdx.x;
    if (i < n4) {
        float4 v = ((const float4*)in)[i];
        ushort4 o;
        o.x = f2bf_rne(v.x); o.y = f2bf_rne(v.y);
        o.z = f2bf_rne(v.z); o.w = f2bf_rne(v.w);
        ((ushort4*)out)[i] = o;
    }
}

// ---------- NT bf16 GEMM: C[m,n] = scale * sum_k A[m,k]*B[n,k] + bias[n] ----------
// 128x128 tile, BK=64, 256 threads = 4 waves in 2x2, 64x64 per wave,
// 4x4 MFMA 16x16x32 tiles per wave, two K-halves per LDS stage.
// LDS layout XOR-swizzled in 16B granules: data (row, kg) lives at granule
// row*8 + (kg ^ (row & 7)).  Swizzle is applied to the GLOBAL SOURCE each
// lane DMAs (global_load_lds dst is HW-pinned to base + lane*16), so LDS
// writes stay lane-ordered/contiguous while ds_read_b128 fragment reads
// spread 16 consecutive rows across all 8 bank groups (2-way = free, m136).
template <typename OutT>
__global__ __launch_bounds__(256) void gemm_nt_bf16(
    const unsigned short* __restrict__ A, int lda, long long strideA,
    const unsigned short* __restrict__ B, int ldb, long long strideB,
    OutT* __restrict__ C, int ldc, long long strideC,
    const float* __restrict__ bias, float scale, int K)
{
    __shared__ unsigned short shA[128 * 64];
    __shared__ unsigned short shB[128 * 64];

    const int t    = threadIdx.x;
    const int lane = t & 63;
    const int wave = t >> 6;
    const int wm   = (wave & 1) * 64;   // wave row offset in tile
    const int wn   = (wave >> 1) * 64;  // wave col offset in tile
    const int quad = lane >> 4;
    const int l16  = lane & 15;

    const long long batch = blockIdx.z;
    A += batch * strideA;
    B += batch * strideB;
    C += batch * strideC;

    const long long tileM = (long long)blockIdx.y * 128;
    const long long tileN = (long long)blockIdx.x * 128;

    f32x4 acc[4][4];
#pragma unroll
    for (int i = 0; i < 4; ++i)
#pragma unroll
        for (int j = 0; j < 4; ++j)
#pragma unroll
            for (int r = 0; r < 4; ++r) acc[i][j][r] = 0.0f;

    for (int k0 = 0; k0 < K; k0 += 64) {
        __syncthreads();   // previous iter's frags consumed before overwrite
#pragma unroll
        for (int p = 0; p < 4; ++p) {
            const int g   = p * 256 + t;        // LDS granule 0..1023 (lane-ordered)
            const int row = g >> 3;             // 0..127
            const int kg  = (g & 7) ^ (row & 7);// swizzled source k-granule
            async_copy16(A + (tileM + row) * (long long)lda + k0 + kg * 8, &shA[g << 3]);
            async_copy16(B + (tileN + row) * (long long)ldb + k0 + kg * 8, &shB[g << 3]);
        }
        __syncthreads();   // compiler drains vmcnt(0) before barrier

#pragma unroll 1           // keep only one K-half's fragments live (VGPR cap)
        for (int h = 0; h < 2; ++h) {
            bf16x8 af[4], bfr[4];
#pragma unroll
            for (int mi = 0; mi < 4; ++mi) {
                const int row = wm + mi * 16 + l16;
                const int kg  = ((h << 2) | quad) ^ (row & 7);
                af[mi] = *(const bf16x8*)(&shA[row * 64 + kg * 8]);
            }
#pragma unroll
            for (int ni = 0; ni < 4; ++ni) {
                const int row = wn + ni * 16 + l16;
                const int kg  = ((h << 2) | quad) ^ (row & 7);
                bfr[ni] = *(const bf16x8*)(&shB[row * 64 + kg * 8]);
            }
#pragma unroll
            for (int mi = 0; mi < 4; ++mi)
#pragma unroll
                for (int ni = 0; ni < 4; ++ni)
                    acc[mi][ni] = __builtin_amdgcn_mfma_f32_16x16x32_bf16(
                        af[mi], bfr[ni], acc[mi][ni], 0, 0, 0);
        }
    }

    // epilogue: D[m][n], m = quad*4 + reg, n = lane&15 within each 16x16 tile
#pragma unroll
    for (int ni = 0; ni < 4; ++ni) {
        const long long gn = tileN + wn + ni * 16 + l16;
        const float bv = bias ? bias[gn] : 0.0f;
#pragma unroll
        for (int mi = 0; mi < 4; ++mi) {
            const long long gm0 = tileM + wm + mi * 16 + quad * 4;
#pragma unroll
            for (int r = 0; r < 4; ++r) {
                float v = acc[mi][ni][r] * scale + bv;
                store_out(C + (gm0 + r) * (long long)ldc + gn, v);
            }
        }
    }
}

// ---------- row softmax in place on [rows][1024] bf16 ----------
__global__ __launch_bounds__(256) void softmax_inplace(unsigned short* __restrict__ att) {
    const long long row = blockIdx.x;
    unsigned short* p = att + row * 1024;
    const int t = threadIdx.x;
    const int wave = t >> 6, lane = t & 63;
    __shared__ float red[4];

    float v[4];
    float mx = -1e30f;
#pragma unroll
    for (int i = 0; i < 4; ++i) { v[i] = bf2f(p[t + i * 256]); mx = fmaxf(mx, v[i]); }
#pragma unroll
    for (int o = 32; o > 0; o >>= 1) mx = fmaxf(mx, __shfl_xor(mx, o));
    if (lane == 0) red[wave] = mx;
    __syncthreads();
    mx = fmaxf(fmaxf(red[0], red[1]), fmaxf(red[2], red[3]));

    float s = 0.f;
#pragma unroll
    for (int i = 0; i < 4; ++i) { v[i] = __expf(v[i] - mx); s += v[i]; }
#pragma unroll
    for (int o = 32; o > 0; o >>= 1) s += __shfl_xor(s, o);
    __syncthreads();   // red[] reuse
    if (lane == 0) red[wave] = s;
    __syncthreads();
    s = red[0] + red[1] + red[2] + red[3];
    const float inv = 1.0f / s;
#pragma unroll
    for (int i = 0; i < 4; ++i) p[t + i * 256] = f2bf_rne(v[i] * inv);
}

// ---------- V transpose: vt[b][d][k] = qkv[b][k][1536+d] ----------
__global__ __launch_bounds__(256) void transpose_v(const unsigned short* __restrict__ qkv,
                                                   unsigned short* __restrict__ vt) {
    __shared__ unsigned short tile[32][33];
    const int b  = blockIdx.z;
    const int k0 = blockIdx.x * 32;
    const int d0 = blockIdx.y * 32;
    const int x  = threadIdx.x;  // 32
    const int y  = threadIdx.y;  // 8
    const unsigned short* src = qkv + (long long)b * 1024 * 2304;
#pragma unroll
    for (int j = 0; j < 4; ++j) {
        int k = k0 + y + j * 8;
        tile[y + j * 8][x] = src[(long long)k * 2304 + 1536 + d0 + x];
    }
    __syncthreads();
    unsigned short* dst = vt + (long long)b * 768 * 1024;
#pragma unroll
    for (int j = 0; j < 4; ++j) {
        int d = d0 + y + j * 8;
        dst[(long long)d * 1024 + k0 + x] = tile[x][y + j * 8];
    }
}

// ---------- launcher ----------
extern "C" void kernel_launch(void* const* d_in, const int* in_sizes, int n_in,
                              void* d_out, int out_size, void* d_ws, size_t ws_size,
                              hipStream_t stream) {
    (void)in_sizes; (void)n_in; (void)out_size; (void)ws_size;

    const float* x     = (const float*)d_in[0];
    const float* w_qkv = (const float*)d_in[1];
    const float* b_qkv = (const float*)d_in[2];
    const float* w_out = (const float*)d_in[3];
    const float* b_out = (const float*)d_in[4];
    float* out = (float*)d_out;

    const int B = 16, S = 1024, D = 768;
    const long long MS = (long long)B * S;  // 16384 rows

    // workspace layout (bf16 = ushort), all 16B aligned
    unsigned short* xb   = (unsigned short*)d_ws;          // [16384][768]
    unsigned short* wqb  = xb   + MS * D;                  // [2304][768]
    unsigned short* wob  = wqb  + 3LL * D * D;             // [768][768]
    unsigned short* qkvb = wob  + (long long)D * D;        // [16384][2304]
    unsigned short* att  = qkvb + MS * 3 * D;              // [16][1024][1024]
    unsigned short* vt   = att  + (long long)B * S * S;    // [16][768][1024]
    unsigned short* ob   = vt   + (long long)B * D * S;    // [16384][768]

    // 1) converts
    {
        int n4 = (int)(MS * D / 4);
        cvt_f32_bf16<<<(n4 + 255) / 256, 256, 0, stream>>>(x, xb, n4);
        n4 = 3 * D * D / 4;
        cvt_f32_bf16<<<(n4 + 255) / 256, 256, 0, stream>>>(w_qkv, wqb, n4);
        n4 = D * D / 4;
        cvt_f32_bf16<<<(n4 + 255) / 256, 256, 0, stream>>>(w_out, wob, n4);
    }

    // 2) QKV = x @ Wqkv^T + b   [16384, 2304]
    gemm_nt_bf16<unsigned short><<<dim3(3 * D / 128, MS / 128, 1), 256, 0, stream>>>(
        xb, D, 0, wqb, D, 0, qkvb, 3 * D, 0, b_qkv, 1.0f, D);

    // 3) logits = scale * Q @ K^T   per batch [1024, 1024]
    const float scale = 0.03608439182435162f;  // 1/sqrt(768)
    gemm_nt_bf16<unsigned short><<<dim3(S / 128, S / 128, B), 256, 0, stream>>>(
        qkvb,     3 * D, (long long)S * 3 * D,
        qkvb + D, 3 * D, (long long)S * 3 * D,
        att, S, (long long)S * S, nullptr, scale, D);

    // 4) softmax rows in place
    softmax_inplace<<<(int)MS, 256, 0, stream>>>(att);

    // 5) vt[b][d][k] = v[b][k][d]
    transpose_v<<<dim3(S / 32, D / 32, B), dim3(32, 8), 0, stream>>>(qkvb, vt);

    // 6) O = P @ V   per batch [1024, 768]
    gemm_nt_bf16<unsigned short><<<dim3(D / 128, S / 128, B), 256, 0, stream>>>(
        att, S, (long long)S * S,
        vt,  S, (long long)D * S,
        ob,  D, (long long)S * D, nullptr, 1.0f, S);

    // 7) out = O @ Wout^T + b   [16384, 768] fp32
    gemm_nt_bf16<float><<<dim3(D / 128, MS / 128, 1), 256, 0, stream>>>(
        ob, D, 0, wob, D, 0, out, D, 0, b_out, 1.0f, D);
}

// Round 3
// 346.426 us; speedup vs baseline: 1.0896x; 1.0051x over previous
//
#include <hip/hip_runtime.h>
#include <hip/hip_bf16.h>
#include <math.h>

// ---------- types ----------
typedef __attribute__((ext_vector_type(8))) short bf16x8;   // 8 bf16 in 4 VGPRs
typedef __attribute__((ext_vector_type(4))) float f32x4;

// ---------- helpers ----------
__device__ __forceinline__ unsigned short f2bf_rne(float f) {
    union { float f; unsigned u; } x; x.f = f;
    unsigned r = x.u + 0x7FFFu + ((x.u >> 16) & 1u);
    return (unsigned short)(r >> 16);
}
__device__ __forceinline__ float bf2f(unsigned short h) {
    union { unsigned u; float f; } x; x.u = ((unsigned)h) << 16;
    return x.f;
}

// 4 consecutive elements per lane (transposed-MFMA epilogue): 8B bf16 / 16B f32
__device__ __forceinline__ void store4(unsigned short* p, float v0, float v1, float v2, float v3) {
    ushort4 o; o.x = f2bf_rne(v0); o.y = f2bf_rne(v1); o.z = f2bf_rne(v2); o.w = f2bf_rne(v3);
    *(ushort4*)p = o;          // 8 B store, gn0 % 4 == 0 -> aligned
}
__device__ __forceinline__ void store4(float* p, float v0, float v1, float v2, float v3) {
    float4 o; o.x = v0; o.y = v1; o.z = v2; o.w = v3;
    *(float4*)p = o;           // 16 B store
}

__device__ __forceinline__ void async_copy16(const void* g, void* l) {
    __builtin_amdgcn_global_load_lds(
        (const __attribute__((address_space(1))) void*)g,
        (__attribute__((address_space(3))) void*)l, 16, 0, 0);
}

// ---------- fused fp32 -> bf16 converts (x, w_qkv, w_out in one launch) ----------
__global__ __launch_bounds__(256) void cvt_all(
    const float* __restrict__ x,  const float* __restrict__ wq, const float* __restrict__ wo,
    unsigned short* __restrict__ xb, unsigned short* __restrict__ wqb, unsigned short* __restrict__ wob,
    int n4x, int n4q, int n4o)
{
    int j = blockIdx.x * 256 + threadIdx.x;
    const float* in; unsigned short* out;
    if (j < n4x) { in = x; out = xb; }
    else {
        j -= n4x;
        if (j < n4q) { in = wq; out = wqb; }
        else { j -= n4q; if (j >= n4o) return; in = wo; out = wob; }
    }
    float4 v = ((const float4*)in)[j];
    ushort4 o;
    o.x = f2bf_rne(v.x); o.y = f2bf_rne(v.y);
    o.z = f2bf_rne(v.z); o.w = f2bf_rne(v.w);
    ((ushort4*)out)[j] = o;
}

// ---------- NT bf16 GEMM: C[m,n] = scale * sum_k A[m,k]*B[n,k] + bias[n] ----------
// 128x128 tile, BK=64, 256 threads = 4 waves (2x2), 64x64 per wave,
// 4x4 MFMA 16x16x32 tiles per wave, two K-halves per LDS stage.
// LDS XOR-swizzled in 16B granules (conflict-free, verified R2: SQ_LDS_BANK_CONFLICT=0).
// MFMA operands SWAPPED (D = B-frag x A-frag = C^T fragment): with the C/D layout
// col=lane&15, row=quad*4+reg, a lane's 4 acc values are 4 CONSECUTIVE n -> each
// lane stores 8B (bf16) / 16B (f32) contiguous; 16 wide stores replace 64 2B stores.
template <typename OutT>
__global__ __launch_bounds__(256, 4) void gemm_nt_bf16(
    const unsigned short* __restrict__ A, int lda, long long strideA,
    const unsigned short* __restrict__ B, int ldb, long long strideB,
    OutT* __restrict__ C, int ldc, long long strideC,
    const float* __restrict__ bias, float scale, int K)
{
    __shared__ unsigned short shA[128 * 64];
    __shared__ unsigned short shB[128 * 64];

    const int t    = threadIdx.x;
    const int lane = t & 63;
    const int wave = t >> 6;
    const int wm   = (wave & 1) * 64;   // wave row offset in tile
    const int wn   = (wave >> 1) * 64;  // wave col offset in tile
    const int quad = lane >> 4;
    const int l16  = lane & 15;

    const long long batch = blockIdx.z;
    A += batch * strideA;
    B += batch * strideB;
    C += batch * strideC;

    const long long tileM = (long long)blockIdx.y * 128;
    const long long tileN = (long long)blockIdx.x * 128;

    f32x4 acc[4][4];
#pragma unroll
    for (int i = 0; i < 4; ++i)
#pragma unroll
        for (int j = 0; j < 4; ++j)
#pragma unroll
            for (int r = 0; r < 4; ++r) acc[i][j][r] = 0.0f;

    for (int k0 = 0; k0 < K; k0 += 64) {
        __syncthreads();   // previous iter's frags consumed before overwrite
#pragma unroll
        for (int p = 0; p < 4; ++p) {
            const int g   = p * 256 + t;        // LDS granule 0..1023 (lane-ordered)
            const int row = g >> 3;             // 0..127
            const int kg  = (g & 7) ^ (row & 7);// swizzled source k-granule
            async_copy16(A + (tileM + row) * (long long)lda + k0 + kg * 8, &shA[g << 3]);
            async_copy16(B + (tileN + row) * (long long)ldb + k0 + kg * 8, &shB[g << 3]);
        }
        __syncthreads();   // compiler drains vmcnt(0) before barrier

#pragma unroll 1           // keep only one K-half's fragments live (VGPR cap)
        for (int h = 0; h < 2; ++h) {
            bf16x8 af[4], bfr[4];
#pragma unroll
            for (int mi = 0; mi < 4; ++mi) {
                const int row = wm + mi * 16 + l16;
                const int kg  = ((h << 2) | quad) ^ (row & 7);
                af[mi] = *(const bf16x8*)(&shA[row * 64 + kg * 8]);
            }
#pragma unroll
            for (int ni = 0; ni < 4; ++ni) {
                const int row = wn + ni * 16 + l16;
                const int kg  = ((h << 2) | quad) ^ (row & 7);
                bfr[ni] = *(const bf16x8*)(&shB[row * 64 + kg * 8]);
            }
#pragma unroll
            for (int mi = 0; mi < 4; ++mi)
#pragma unroll
                for (int ni = 0; ni < 4; ++ni)
                    acc[mi][ni] = __builtin_amdgcn_mfma_f32_16x16x32_bf16(
                        bfr[ni], af[mi], acc[mi][ni], 0, 0, 0);   // operands swapped: D = C^T frag
        }
    }

    // epilogue: D holds C^T tile: lane -> m = l16 (fixed row), n = quad*4 + {0..3}
#pragma unroll
    for (int mi = 0; mi < 4; ++mi) {
        const long long gm = tileM + wm + mi * 16 + l16;
#pragma unroll
        for (int ni = 0; ni < 4; ++ni) {
            const long long gn0 = tileN + wn + ni * 16 + quad * 4;
            float b0 = 0.f, b1 = 0.f, b2 = 0.f, b3 = 0.f;
            if (bias) {
                float4 bv = *(const float4*)&bias[gn0];
                b0 = bv.x; b1 = bv.y; b2 = bv.z; b3 = bv.w;
            }
            const f32x4 a = acc[mi][ni];
            store4(C + gm * (long long)ldc + gn0,
                   a[0] * scale + b0, a[1] * scale + b1,
                   a[2] * scale + b2, a[3] * scale + b3);
        }
    }
}

// ---------- row softmax in place on [rows][1024] bf16 ----------
__global__ __launch_bounds__(256) void softmax_inplace(unsigned short* __restrict__ att) {
    const long long row = blockIdx.x;
    unsigned short* p = att + row * 1024;
    const int t = threadIdx.x;
    const int wave = t >> 6, lane = t & 63;
    __shared__ float red[4];

    float v[4];
    float mx = -1e30f;
#pragma unroll
    for (int i = 0; i < 4; ++i) { v[i] = bf2f(p[t + i * 256]); mx = fmaxf(mx, v[i]); }
#pragma unroll
    for (int o = 32; o > 0; o >>= 1) mx = fmaxf(mx, __shfl_xor(mx, o));
    if (lane == 0) red[wave] = mx;
    __syncthreads();
    mx = fmaxf(fmaxf(red[0], red[1]), fmaxf(red[2], red[3]));

    float s = 0.f;
#pragma unroll
    for (int i = 0; i < 4; ++i) { v[i] = __expf(v[i] - mx); s += v[i]; }
#pragma unroll
    for (int o = 32; o > 0; o >>= 1) s += __shfl_xor(s, o);
    __syncthreads();   // red[] reuse
    if (lane == 0) red[wave] = s;
    __syncthreads();
    s = red[0] + red[1] + red[2] + red[3];
    const float inv = 1.0f / s;
#pragma unroll
    for (int i = 0; i < 4; ++i) p[t + i * 256] = f2bf_rne(v[i] * inv);
}

// ---------- V transpose: vt[b][d][k] = qkv[b][k][1536+d] ----------
__global__ __launch_bounds__(256) void transpose_v(const unsigned short* __restrict__ qkv,
                                                   unsigned short* __restrict__ vt) {
    __shared__ unsigned short tile[32][33];
    const int b  = blockIdx.z;
    const int k0 = blockIdx.x * 32;
    const int d0 = blockIdx.y * 32;
    const int x  = threadIdx.x;  // 32
    const int y  = threadIdx.y;  // 8
    const unsigned short* src = qkv + (long long)b * 1024 * 2304;
#pragma unroll
    for (int j = 0; j < 4; ++j) {
        int k = k0 + y + j * 8;
        tile[y + j * 8][x] = src[(long long)k * 2304 + 1536 + d0 + x];
    }
    __syncthreads();
    unsigned short* dst = vt + (long long)b * 768 * 1024;
#pragma unroll
    for (int j = 0; j < 4; ++j) {
        int d = d0 + y + j * 8;
        dst[(long long)d * 1024 + k0 + x] = tile[x][y + j * 8];
    }
}

// ---------- launcher ----------
extern "C" void kernel_launch(void* const* d_in, const int* in_sizes, int n_in,
                              void* d_out, int out_size, void* d_ws, size_t ws_size,
                              hipStream_t stream) {
    (void)in_sizes; (void)n_in; (void)out_size; (void)ws_size;

    const float* x     = (const float*)d_in[0];
    const float* w_qkv = (const float*)d_in[1];
    const float* b_qkv = (const float*)d_in[2];
    const float* w_out = (const float*)d_in[3];
    const float* b_out = (const float*)d_in[4];
    float* out = (float*)d_out;

    const int B = 16, S = 1024, D = 768;
    const long long MS = (long long)B * S;  // 16384 rows

    // workspace layout (bf16 = ushort), all 16B aligned
    unsigned short* xb   = (unsigned short*)d_ws;          // [16384][768]
    unsigned short* wqb  = xb   + MS * D;                  // [2304][768]
    unsigned short* wob  = wqb  + 3LL * D * D;             // [768][768]
    unsigned short* qkvb = wob  + (long long)D * D;        // [16384][2304]
    unsigned short* att  = qkvb + MS * 3 * D;              // [16][1024][1024]
    unsigned short* vt   = att  + (long long)B * S * S;    // [16][768][1024]
    unsigned short* ob   = vt   + (long long)B * D * S;    // [16384][768]

    // 1) converts (single launch)
    {
        const int n4x = (int)(MS * D / 4);
        const int n4q = 3 * D * D / 4;
        const int n4o = D * D / 4;
        const int tot = n4x + n4q + n4o;
        cvt_all<<<(tot + 255) / 256, 256, 0, stream>>>(x, w_qkv, w_out, xb, wqb, wob,
                                                      n4x, n4q, n4o);
    }

    // 2) QKV = x @ Wqkv^T + b   [16384, 2304]
    gemm_nt_bf16<unsigned short><<<dim3(3 * D / 128, MS / 128, 1), 256, 0, stream>>>(
        xb, D, 0, wqb, D, 0, qkvb, 3 * D, 0, b_qkv, 1.0f, D);

    // 3) logits = scale * Q @ K^T   per batch [1024, 1024]
    const float scale = 0.03608439182435162f;  // 1/sqrt(768)
    gemm_nt_bf16<unsigned short><<<dim3(S / 128, S / 128, B), 256, 0, stream>>>(
        qkvb,     3 * D, (long long)S * 3 * D,
        qkvb + D, 3 * D, (long long)S * 3 * D,
        att, S, (long long)S * S, nullptr, scale, D);

    // 4) softmax rows in place
    softmax_inplace<<<(int)MS, 256, 0, stream>>>(att);

    // 5) vt[b][d][k] = v[b][k][d]
    transpose_v<<<dim3(S / 32, D / 32, B), dim3(32, 8), 0, stream>>>(qkvb, vt);

    // 6) O = P @ V   per batch [1024, 768]
    gemm_nt_bf16<unsigned short><<<dim3(D / 128, S / 128, B), 256, 0, stream>>>(
        att, S, (long long)S * S,
        vt,  S, (long long)D * S,
        ob,  D, (long long)S * D, nullptr, 1.0f, S);

    // 7) out = O @ Wout^T + b   [16384, 768] fp32
    gemm_nt_bf16<float><<<dim3(D / 128, MS / 128, 1), 256, 0, stream>>>(
        ob, D, 0, wob, D, 0, out, D, 0, b_out, 1.0f, D);
}